// Round 3
// baseline (56.057 us; speedup 1.0000x reference)
//
#include <hip/hip_runtime.h>
#include <hip/hip_bf16.h>
#include <math.h>

// Algebraic reduction of the reference:
//   Ip = I, In = 0  (identity matrix has no negative entries)
//   ub_mult = diag(d_ub) with d_ub >= 0, so max(.,0)@ub + min(.,0)@lb = d_ub*ub
//   lb_mult = diag(d_lb) with d_lb >= 0, so ... = d_lb*lb
//   out_ub = layer_ub_bias + d_ub*ub
//   out_lb = d_lb*lb
// Everything is elementwise over N=4096.

__global__ void ReluVerifier_8486855377235_kernel(const float* __restrict__ lb,
                                                  const float* __restrict__ ub,
                                                  const float* __restrict__ alpha,
                                                  float* __restrict__ out,
                                                  int n) {
    int i = blockIdx.x * blockDim.x + threadIdx.x;
    if (i >= n) return;

    float l = lb[i];
    float u = ub[i];
    float a = alpha[i];

    // slope = clamp(ub/(ub-lb), min=0); lb < ub guaranteed so (u-l) > 0
    float s = fmaxf(u / (u - l), 0.0f);

    // upper bound: d_ub = (lb>0) ? 1 : slope; bias = (lb>0) ? 0 : -slope*lb
    // out_ub = bias + d_ub * ub  (same operation order as the reference)
    float out_ub = (l > 0.0f) ? u : ((-s * l) + s * u);

    // lower bound: d_lb = (ub<0) ? 0 : (lb>0) ? 1 : sigmoid(alpha); bias = 0
    float sig = 1.0f / (1.0f + expf(-a));
    float d_lb = (u < 0.0f) ? 0.0f : ((l > 0.0f) ? 1.0f : sig);
    float out_lb = d_lb * l;

    out[i] = out_ub;       // out_ub occupies the first n elements
    out[n + i] = out_lb;   // out_lb the next n
}

extern "C" void kernel_launch(void* const* d_in, const int* in_sizes, int n_in,
                              void* d_out, int out_size, void* d_ws, size_t ws_size,
                              hipStream_t stream) {
    const float* lb = (const float*)d_in[0];
    const float* ub = (const float*)d_in[1];
    const float* alpha = (const float*)d_in[2];
    float* out = (float*)d_out;
    int n = in_sizes[0];  // 4096

    int block = 256;
    int grid = (n + block - 1) / block;  // 16 blocks
    ReluVerifier_8486855377235_kernel<<<grid, block, 0, stream>>>(lb, ub, alpha, out, n);
}